// Round 1
// baseline (475.598 us; speedup 1.0000x reference)
//
#include <hip/hip_runtime.h>
#include <hip/hip_bf16.h>

// B=4, S=2048, D=1024. out = softmax((x@Wk)(x@Wq)^T / 32) @ (x@Wv), fp32 out.

typedef __attribute__((ext_vector_type(8))) short bf16x8;
typedef __attribute__((ext_vector_type(4))) float f32x4;

__device__ __forceinline__ unsigned short f2bf(float f) {
    unsigned int u = __float_as_uint(f);
    u += 0x7fff + ((u >> 16) & 1);   // RNE
    return (unsigned short)(u >> 16);
}

#define LP 40  // LDS pitch in bf16 elems: 80B rows -> 16B aligned, ~2-way bank alias

// ------------- projection GEMM: x[8192,1024](f32) @ w[1024,1024](f32) -> bf16 -------------
__global__ __launch_bounds__(256) void proj_gemm(
    const float* __restrict__ x,
    const float* __restrict__ w0, const float* __restrict__ w1, const float* __restrict__ w2,
    unsigned short* __restrict__ o0, unsigned short* __restrict__ o1, unsigned short* __restrict__ o2)
{
    __shared__ unsigned short As[128][LP];
    __shared__ unsigned short Bs[128][LP];   // stored transposed: Bs[n][k]
    const int tid  = threadIdx.x;
    const int bm   = blockIdx.y * 128;
    const int bn   = blockIdx.x * 128;
    const float* w          = (blockIdx.z == 0) ? w0 : (blockIdx.z == 1 ? w1 : w2);
    unsigned short* out     = (blockIdx.z == 0) ? o0 : (blockIdx.z == 1 ? o1 : o2);

    const int lane = tid & 63;
    const int wave = tid >> 6;
    const int wm   = (wave >> 1) * 64;
    const int wn   = (wave & 1) * 64;
    const int lr   = lane & 15;
    const int kg   = lane >> 4;      // 0..3

    f32x4 acc[4][4] = {};

    const int ac4 = tid & 7;    // A: k-chunk of 4 floats
    const int ar0 = tid >> 3;   // A: row 0..31
    const int bn4 = tid & 31;   // B: n-chunk of 4 floats
    const int bk0 = tid >> 5;   // B: k 0..7

    for (int k0 = 0; k0 < 1024; k0 += 32) {
        #pragma unroll
        for (int i = 0; i < 4; i++) {
            int r = ar0 + i * 32;
            float4 v = *reinterpret_cast<const float4*>(&x[(size_t)(bm + r) * 1024 + k0 + ac4 * 4]);
            ushort4 u = { f2bf(v.x), f2bf(v.y), f2bf(v.z), f2bf(v.w) };
            *reinterpret_cast<ushort4*>(&As[r][ac4 * 4]) = u;
        }
        #pragma unroll
        for (int i = 0; i < 4; i++) {
            int kk = bk0 + i * 8;
            float4 v = *reinterpret_cast<const float4*>(&w[(size_t)(k0 + kk) * 1024 + bn + bn4 * 4]);
            Bs[bn4 * 4 + 0][kk] = f2bf(v.x);
            Bs[bn4 * 4 + 1][kk] = f2bf(v.y);
            Bs[bn4 * 4 + 2][kk] = f2bf(v.z);
            Bs[bn4 * 4 + 3][kk] = f2bf(v.w);
        }
        __syncthreads();
        bf16x8 a[4], b[4];
        #pragma unroll
        for (int mi = 0; mi < 4; mi++)
            a[mi] = *reinterpret_cast<const bf16x8*>(&As[wm + mi * 16 + lr][kg * 8]);
        #pragma unroll
        for (int ni = 0; ni < 4; ni++)
            b[ni] = *reinterpret_cast<const bf16x8*>(&Bs[wn + ni * 16 + lr][kg * 8]);
        #pragma unroll
        for (int mi = 0; mi < 4; mi++)
            #pragma unroll
            for (int ni = 0; ni < 4; ni++)
                acc[mi][ni] = __builtin_amdgcn_mfma_f32_16x16x32_bf16(a[mi], b[ni], acc[mi][ni], 0, 0, 0);
        __syncthreads();
    }
    #pragma unroll
    for (int mi = 0; mi < 4; mi++)
        #pragma unroll
        for (int ni = 0; ni < 4; ni++)
            #pragma unroll
            for (int r = 0; r < 4; r++) {
                int row = bm + wm + mi * 16 + kg * 4 + r;
                int col = bn + wn + ni * 16 + lr;
                out[(size_t)row * 1024 + col] = f2bf(acc[mi][ni][r]);
            }
}

// ------------- scores: per batch vk[2048,1024] @ vq[2048,1024]^T / 32 -> f32 -------------
__global__ __launch_bounds__(256) void scores_gemm(
    const unsigned short* __restrict__ vk, const unsigned short* __restrict__ vq,
    float* __restrict__ scores)
{
    __shared__ unsigned short As[128][LP];
    __shared__ unsigned short Bs[128][LP];
    const int tid = threadIdx.x;
    const int bm  = blockIdx.y * 128;   // s
    const int bn  = blockIdx.x * 128;   // t
    const unsigned short* A  = vk + (size_t)blockIdx.z * 2048 * 1024;
    const unsigned short* Bp = vq + (size_t)blockIdx.z * 2048 * 1024;
    float* out = scores + (size_t)blockIdx.z * 2048 * 2048;

    const int lane = tid & 63;
    const int wave = tid >> 6;
    const int wm   = (wave >> 1) * 64;
    const int wn   = (wave & 1) * 64;
    const int lr   = lane & 15;
    const int kg   = lane >> 4;

    f32x4 acc[4][4] = {};

    const int c  = tid & 3;    // 16B chunk in row (8 bf16)
    const int r0 = tid >> 2;   // 0..63

    for (int k0 = 0; k0 < 1024; k0 += 32) {
        #pragma unroll
        for (int i = 0; i < 2; i++) {
            int r = r0 + i * 64;
            *reinterpret_cast<uint4*>(&As[r][c * 8]) =
                *reinterpret_cast<const uint4*>(&A[(size_t)(bm + r) * 1024 + k0 + c * 8]);
            *reinterpret_cast<uint4*>(&Bs[r][c * 8]) =
                *reinterpret_cast<const uint4*>(&Bp[(size_t)(bn + r) * 1024 + k0 + c * 8]);
        }
        __syncthreads();
        bf16x8 a[4], b[4];
        #pragma unroll
        for (int mi = 0; mi < 4; mi++)
            a[mi] = *reinterpret_cast<const bf16x8*>(&As[wm + mi * 16 + lr][kg * 8]);
        #pragma unroll
        for (int ni = 0; ni < 4; ni++)
            b[ni] = *reinterpret_cast<const bf16x8*>(&Bs[wn + ni * 16 + lr][kg * 8]);
        #pragma unroll
        for (int mi = 0; mi < 4; mi++)
            #pragma unroll
            for (int ni = 0; ni < 4; ni++)
                acc[mi][ni] = __builtin_amdgcn_mfma_f32_16x16x32_bf16(a[mi], b[ni], acc[mi][ni], 0, 0, 0);
        __syncthreads();
    }
    #pragma unroll
    for (int mi = 0; mi < 4; mi++)
        #pragma unroll
        for (int ni = 0; ni < 4; ni++)
            #pragma unroll
            for (int r = 0; r < 4; r++) {
                int row = bm + wm + mi * 16 + kg * 4 + r;
                int col = bn + wn + ni * 16 + lr;
                out[(size_t)row * 2048 + col] = acc[mi][ni][r] * 0.03125f;
            }
}

// ------------- softmax over last axis; writes bf16 P in-place (first half of each f32 row) -------------
__global__ __launch_bounds__(256) void softmax_kernel(float* __restrict__ scores)
{
    const size_t row = blockIdx.x;
    float* p = scores + row * 2048;
    const int tid  = threadIdx.x;
    const int lane = tid & 63;
    const int wave = tid >> 6;

    float4 v0 = *reinterpret_cast<const float4*>(&p[tid * 8]);
    float4 v1 = *reinterpret_cast<const float4*>(&p[tid * 8 + 4]);
    float v[8] = { v0.x, v0.y, v0.z, v0.w, v1.x, v1.y, v1.z, v1.w };

    float mx = v[0];
    #pragma unroll
    for (int i = 1; i < 8; i++) mx = fmaxf(mx, v[i]);
    #pragma unroll
    for (int off = 32; off >= 1; off >>= 1) mx = fmaxf(mx, __shfl_xor(mx, off));

    __shared__ float redm[4], reds[4];
    if (lane == 0) redm[wave] = mx;
    __syncthreads();                       // also guarantees all row reads complete
    mx = fmaxf(fmaxf(redm[0], redm[1]), fmaxf(redm[2], redm[3]));

    float e[8], sum = 0.f;
    #pragma unroll
    for (int i = 0; i < 8; i++) { e[i] = __expf(v[i] - mx); sum += e[i]; }
    #pragma unroll
    for (int off = 32; off >= 1; off >>= 1) sum += __shfl_xor(sum, off);
    if (lane == 0) reds[wave] = sum;
    __syncthreads();
    const float inv = 1.0f / (reds[0] + reds[1] + reds[2] + reds[3]);

    unsigned short o[8];
    #pragma unroll
    for (int i = 0; i < 8; i++) o[i] = f2bf(e[i] * inv);
    uint4 packed;
    packed.x = (unsigned)o[0] | ((unsigned)o[1] << 16);
    packed.y = (unsigned)o[2] | ((unsigned)o[3] << 16);
    packed.z = (unsigned)o[4] | ((unsigned)o[5] << 16);
    packed.w = (unsigned)o[6] | ((unsigned)o[7] << 16);
    reinterpret_cast<uint4*>(p)[tid] = packed;   // bf16 row occupies first 4KB of the 8KB f32 row
}

// ------------- PV: per batch P[2048,2048](bf16, pitch 4096) @ vv[2048,1024](bf16) -> f32 out -------------
__global__ __launch_bounds__(256) void pv_gemm(
    const unsigned short* __restrict__ P, const unsigned short* __restrict__ vv,
    float* __restrict__ out)
{
    __shared__ unsigned short As[128][LP];
    __shared__ unsigned short Bs[128][LP];   // transposed: Bs[n][k]
    const int tid = threadIdx.x;
    const int bm  = blockIdx.y * 128;   // s
    const int bn  = blockIdx.x * 128;   // d
    const unsigned short* A = P  + (size_t)blockIdx.z * 2048 * 4096;
    const unsigned short* B = vv + (size_t)blockIdx.z * 2048 * 1024;
    float* o = out + (size_t)blockIdx.z * 2048 * 1024;

    const int lane = tid & 63;
    const int wave = tid >> 6;
    const int wm   = (wave >> 1) * 64;
    const int wn   = (wave & 1) * 64;
    const int lr   = lane & 15;
    const int kg   = lane >> 4;

    f32x4 acc[4][4] = {};

    const int c   = tid & 3;
    const int r0  = tid >> 2;
    const int bn4 = tid & 31;
    const int bk0 = tid >> 5;

    for (int k0 = 0; k0 < 2048; k0 += 32) {
        #pragma unroll
        for (int i = 0; i < 2; i++) {
            int r = r0 + i * 64;
            *reinterpret_cast<uint4*>(&As[r][c * 8]) =
                *reinterpret_cast<const uint4*>(&A[(size_t)(bm + r) * 4096 + k0 + c * 8]);
        }
        #pragma unroll
        for (int i = 0; i < 4; i++) {
            int kk = bk0 + i * 8;
            ushort4 v = *reinterpret_cast<const ushort4*>(&B[(size_t)(k0 + kk) * 1024 + bn + bn4 * 4]);
            Bs[bn4 * 4 + 0][kk] = v.x;
            Bs[bn4 * 4 + 1][kk] = v.y;
            Bs[bn4 * 4 + 2][kk] = v.z;
            Bs[bn4 * 4 + 3][kk] = v.w;
        }
        __syncthreads();
        bf16x8 a[4], b[4];
        #pragma unroll
        for (int mi = 0; mi < 4; mi++)
            a[mi] = *reinterpret_cast<const bf16x8*>(&As[wm + mi * 16 + lr][kg * 8]);
        #pragma unroll
        for (int ni = 0; ni < 4; ni++)
            b[ni] = *reinterpret_cast<const bf16x8*>(&Bs[wn + ni * 16 + lr][kg * 8]);
        #pragma unroll
        for (int mi = 0; mi < 4; mi++)
            #pragma unroll
            for (int ni = 0; ni < 4; ni++)
                acc[mi][ni] = __builtin_amdgcn_mfma_f32_16x16x32_bf16(a[mi], b[ni], acc[mi][ni], 0, 0, 0);
        __syncthreads();
    }
    #pragma unroll
    for (int mi = 0; mi < 4; mi++)
        #pragma unroll
        for (int ni = 0; ni < 4; ni++)
            #pragma unroll
            for (int r = 0; r < 4; r++) {
                int row = bm + wm + mi * 16 + kg * 4 + r;
                int col = bn + wn + ni * 16 + lr;
                o[(size_t)row * 1024 + col] = acc[mi][ni][r];
            }
}

extern "C" void kernel_launch(void* const* d_in, const int* in_sizes, int n_in,
                              void* d_out, int out_size, void* d_ws, size_t ws_size,
                              hipStream_t stream) {
    const float* x  = (const float*)d_in[0];
    const float* wk = (const float*)d_in[1];
    const float* wq = (const float*)d_in[2];
    const float* wv = (const float*)d_in[3];
    float* out = (float*)d_out;

    char* ws = (char*)d_ws;
    unsigned short* vk = (unsigned short*)ws;                                  // 16 MB bf16
    unsigned short* vq = (unsigned short*)(ws + (size_t)16 * 1024 * 1024);     // 16 MB bf16
    unsigned short* vv = (unsigned short*)(ws + (size_t)32 * 1024 * 1024);     // 16 MB bf16
    float* scores      = (float*)(ws + (size_t)48 * 1024 * 1024);              // 64 MB f32

    dim3 blk(256);
    proj_gemm  <<<dim3(8, 64, 3), blk, 0, stream>>>(x, wk, wq, wv, vk, vq, vv);
    scores_gemm<<<dim3(16, 16, 4), blk, 0, stream>>>(vk, vq, scores);
    softmax_kernel<<<dim3(8192), blk, 0, stream>>>(scores);
    pv_gemm    <<<dim3(8, 16, 4), blk, 0, stream>>>((const unsigned short*)scores, vv, out);
}

// Round 2
// 229.662 us; speedup vs baseline: 2.0709x; 2.0709x over previous
//
#include <hip/hip_runtime.h>

// B=4, S=2048, D=1024. out = softmax((x@Wk)(x@Wq)^T / 32) @ (x@Wv), fp32 out.
// Stages: convert x->bf16; transpose W->bf16 [N][K]; proj (m97-style gemm_bt);
// scores (gemm_bt); softmax (in-place bf16 P); PV (gemm_bt vs pre-transposed V).

typedef __attribute__((ext_vector_type(8))) short bf16x8;
typedef __attribute__((ext_vector_type(4))) float f32x4;

__device__ __forceinline__ unsigned short f2bf(float f) {
    unsigned int u = __float_as_uint(f);
    u += 0x7fff + ((u >> 16) & 1);   // RNE
    return (unsigned short)(u >> 16);
}

__device__ __forceinline__ void gld_lds16(const unsigned short* g, unsigned short* l) {
    // 16B per lane, LDS dest = wave-uniform base + lane*16 (linear, no swizzle)
    __builtin_amdgcn_global_load_lds(
        (const __attribute__((address_space(1))) void*)g,
        (__attribute__((address_space(3))) void*)l,
        16, 0, 0);
}

// ---------------- x f32 -> bf16 ----------------
__global__ __launch_bounds__(256) void convert_x(
    const float* __restrict__ x, unsigned short* __restrict__ xb)
{
    const size_t idx = (size_t)blockIdx.x * 256 + threadIdx.x;  // 1M threads x 8 elems
    const float4* xi = reinterpret_cast<const float4*>(x) + idx * 2;
    float4 v0 = xi[0], v1 = xi[1];
    ushort4 a = { f2bf(v0.x), f2bf(v0.y), f2bf(v0.z), f2bf(v0.w) };
    ushort4 b = { f2bf(v1.x), f2bf(v1.y), f2bf(v1.z), f2bf(v1.w) };
    ushort4* xo = reinterpret_cast<ushort4*>(xb) + idx * 2;
    xo[0] = a; xo[1] = b;
}

// ---------------- W [K][N] f32 -> wT [N][K] bf16 (3 weights via z) ----------------
__global__ __launch_bounds__(256) void transpose_w(
    const float* __restrict__ w0, const float* __restrict__ w1, const float* __restrict__ w2,
    unsigned short* __restrict__ wT)
{
    __shared__ unsigned short T[64][72];   // pitch 72 -> 144B rows, 8B-aligned ushort4
    const int z = blockIdx.z;
    const float* w = (z == 0) ? w0 : (z == 1 ? w1 : w2);
    unsigned short* o = wT + (size_t)z * 1024 * 1024;
    const int k0 = blockIdx.y * 64, n0 = blockIdx.x * 64;
    const int tid = threadIdx.x;
    const int r = tid >> 4, c4 = (tid & 15) * 4;
    #pragma unroll
    for (int i = 0; i < 4; i++) {
        int kr = r + i * 16;
        float4 v = *reinterpret_cast<const float4*>(&w[(size_t)(k0 + kr) * 1024 + n0 + c4]);
        T[c4 + 0][kr] = f2bf(v.x);
        T[c4 + 1][kr] = f2bf(v.y);
        T[c4 + 2][kr] = f2bf(v.z);
        T[c4 + 3][kr] = f2bf(v.w);
    }
    __syncthreads();
    #pragma unroll
    for (int i = 0; i < 4; i++) {
        int n = r + i * 16;
        ushort4 v = *reinterpret_cast<const ushort4*>(&T[n][c4]);
        *reinterpret_cast<ushort4*>(&o[(size_t)(n0 + n) * 1024 + k0 + c4]) = v;
    }
}

// ---------------- m97-style 128x128 bf16 B^T GEMM core ----------------
// C[128,128] tile at (bm,bn): C[m,n] = sum_k A[bm+m, k] * B[bn+n, k]
// LDS linear [128][32] bf16; staged via global_load_lds width=16.
__device__ __forceinline__ void gemm_core_128(
    const unsigned short* __restrict__ A, const unsigned short* __restrict__ B,
    int lda, int ldb, int K, int bm, int bn,
    unsigned short* As, unsigned short* Bs, f32x4 acc[4][4])
{
    const int tid  = threadIdx.x;
    const int lane = tid & 63;
    const int wave = tid >> 6;
    const int wm   = (wave >> 1) * 64;
    const int wn   = (wave & 1) * 64;
    const int lr   = lane & 15;
    const int kg   = lane >> 4;

    // staging map: chunk j = i*256+tid -> row j>>2, k-octet (j&3)*8
    const int srow = tid >> 2;            // 0..63 (+64 for i=1)
    const int skc  = (tid & 3) * 8;

    const unsigned short* ga0 = A + (size_t)(bm + srow)      * lda + skc;
    const unsigned short* ga1 = A + (size_t)(bm + srow + 64) * lda + skc;
    const unsigned short* gb0 = B + (size_t)(bn + srow)      * ldb + skc;
    const unsigned short* gb1 = B + (size_t)(bn + srow + 64) * ldb + skc;
    unsigned short* lA0 = As + (wave * 64) * 8;          // wave-uniform bases
    unsigned short* lA1 = As + (256 + wave * 64) * 8;
    unsigned short* lB0 = Bs + (wave * 64) * 8;
    unsigned short* lB1 = Bs + (256 + wave * 64) * 8;

    for (int k0 = 0; k0 < K; k0 += 32) {
        gld_lds16(ga0 + k0, lA0);
        gld_lds16(ga1 + k0, lA1);
        gld_lds16(gb0 + k0, lB0);
        gld_lds16(gb1 + k0, lB1);
        __syncthreads();
        bf16x8 af[4], bfr[4];
        #pragma unroll
        for (int mi = 0; mi < 4; mi++)
            af[mi] = *reinterpret_cast<const bf16x8*>(&As[(wm + mi * 16 + lr) * 32 + kg * 8]);
        #pragma unroll
        for (int ni = 0; ni < 4; ni++)
            bfr[ni] = *reinterpret_cast<const bf16x8*>(&Bs[(wn + ni * 16 + lr) * 32 + kg * 8]);
        #pragma unroll
        for (int mi = 0; mi < 4; mi++)
            #pragma unroll
            for (int ni = 0; ni < 4; ni++)
                acc[mi][ni] = __builtin_amdgcn_mfma_f32_16x16x32_bf16(af[mi], bfr[ni], acc[mi][ni], 0, 0, 0);
        __syncthreads();
    }
}

// ---------------- projections: xb[8192,1024] @ wT[z]^T -> vk/vq (bf16), vvT (bf16 transposed) ----------------
__global__ __launch_bounds__(256) void proj_gemm(
    const unsigned short* __restrict__ xb, const unsigned short* __restrict__ wT,
    unsigned short* __restrict__ vk, unsigned short* __restrict__ vq,
    unsigned short* __restrict__ vvT)
{
    __shared__ unsigned short As[128 * 32], Bs[128 * 32];
    const int bm = blockIdx.y * 128, bn = blockIdx.x * 128, z = blockIdx.z;
    const unsigned short* B = wT + (size_t)z * 1024 * 1024;
    f32x4 acc[4][4] = {};
    gemm_core_128(xb, B, 1024, 1024, 1024, bm, bn, As, Bs, acc);

    const int tid = threadIdx.x, lane = tid & 63, wave = tid >> 6;
    const int wm = (wave >> 1) * 64, wn = (wave & 1) * 64;
    const int lr = lane & 15, kg = lane >> 4;

    if (z < 2) {
        unsigned short* out = z ? vq : vk;
        #pragma unroll
        for (int mi = 0; mi < 4; mi++)
            #pragma unroll
            for (int ni = 0; ni < 4; ni++)
                #pragma unroll
                for (int r = 0; r < 4; r++)
                    out[(size_t)(bm + wm + mi * 16 + kg * 4 + r) * 1024 + bn + wn + ni * 16 + lr]
                        = f2bf(acc[mi][ni][r]);
    } else {
        // write V transposed per batch: vvT[b][d=col][t=row'] (tiles never span batches: 2048 % 128 == 0)
        const int batch = bm >> 11;
        const int rb0 = (bm & 2047) + wm;
        unsigned short* o = vvT + (size_t)batch * 1024 * 2048;
        #pragma unroll
        for (int mi = 0; mi < 4; mi++)
            #pragma unroll
            for (int ni = 0; ni < 4; ni++) {
                ushort4 v = { f2bf(acc[mi][ni][0]), f2bf(acc[mi][ni][1]),
                              f2bf(acc[mi][ni][2]), f2bf(acc[mi][ni][3]) };
                *reinterpret_cast<ushort4*>(
                    &o[(size_t)(bn + wn + ni * 16 + lr) * 2048 + rb0 + mi * 16 + kg * 4]) = v;
            }
    }
}

// ---------------- scores: vk[b] @ vq[b]^T / 32 -> f32 [2048][2048] ----------------
__global__ __launch_bounds__(256) void scores_gemm(
    const unsigned short* __restrict__ vk, const unsigned short* __restrict__ vq,
    float* __restrict__ scores)
{
    __shared__ unsigned short As[128 * 32], Bs[128 * 32];
    const int bm = blockIdx.y * 128, bn = blockIdx.x * 128, z = blockIdx.z;
    const unsigned short* A = vk + (size_t)z * 2048 * 1024;
    const unsigned short* B = vq + (size_t)z * 2048 * 1024;
    float* out = scores + (size_t)z * 2048 * 2048;
    f32x4 acc[4][4] = {};
    gemm_core_128(A, B, 1024, 1024, 1024, bm, bn, As, Bs, acc);

    const int tid = threadIdx.x, lane = tid & 63, wave = tid >> 6;
    const int wm = (wave >> 1) * 64, wn = (wave & 1) * 64;
    const int lr = lane & 15, kg = lane >> 4;
    #pragma unroll
    for (int mi = 0; mi < 4; mi++)
        #pragma unroll
        for (int ni = 0; ni < 4; ni++)
            #pragma unroll
            for (int r = 0; r < 4; r++)
                out[(size_t)(bm + wm + mi * 16 + kg * 4 + r) * 2048 + bn + wn + ni * 16 + lr]
                    = acc[mi][ni][r] * 0.03125f;
}

// ---------------- softmax over last axis; bf16 P written in-place over first half of each f32 row ----------------
__global__ __launch_bounds__(256) void softmax_kernel(float* __restrict__ scores)
{
    const size_t row = blockIdx.x;
    float* p = scores + row * 2048;
    const int tid  = threadIdx.x;
    const int lane = tid & 63;
    const int wave = tid >> 6;

    float4 v0 = *reinterpret_cast<const float4*>(&p[tid * 8]);
    float4 v1 = *reinterpret_cast<const float4*>(&p[tid * 8 + 4]);
    float v[8] = { v0.x, v0.y, v0.z, v0.w, v1.x, v1.y, v1.z, v1.w };

    float mx = v[0];
    #pragma unroll
    for (int i = 1; i < 8; i++) mx = fmaxf(mx, v[i]);
    #pragma unroll
    for (int off = 32; off >= 1; off >>= 1) mx = fmaxf(mx, __shfl_xor(mx, off));

    __shared__ float redm[4], reds[4];
    if (lane == 0) redm[wave] = mx;
    __syncthreads();                      // all row reads complete before any in-place write
    mx = fmaxf(fmaxf(redm[0], redm[1]), fmaxf(redm[2], redm[3]));

    float e[8], sum = 0.f;
    #pragma unroll
    for (int i = 0; i < 8; i++) { e[i] = __expf(v[i] - mx); sum += e[i]; }
    #pragma unroll
    for (int off = 32; off >= 1; off >>= 1) sum += __shfl_xor(sum, off);
    if (lane == 0) reds[wave] = sum;
    __syncthreads();
    const float inv = 1.0f / (reds[0] + reds[1] + reds[2] + reds[3]);

    unsigned short o[8];
    #pragma unroll
    for (int i = 0; i < 8; i++) o[i] = f2bf(e[i] * inv);
    uint4 packed;
    packed.x = (unsigned)o[0] | ((unsigned)o[1] << 16);
    packed.y = (unsigned)o[2] | ((unsigned)o[3] << 16);
    packed.z = (unsigned)o[4] | ((unsigned)o[5] << 16);
    packed.w = (unsigned)o[6] | ((unsigned)o[7] << 16);
    reinterpret_cast<uint4*>(p)[tid] = packed;   // bf16 row = first 4KB of the 8KB f32 row
}

// ---------------- PV: P[2048,2048] (bf16, pitch 4096) @ vvT[b]^T -> f32 out ----------------
__global__ __launch_bounds__(256) void pv_gemm(
    const unsigned short* __restrict__ P, const unsigned short* __restrict__ vvT,
    float* __restrict__ out)
{
    __shared__ unsigned short As[128 * 32], Bs[128 * 32];
    const int bm = blockIdx.y * 128, bn = blockIdx.x * 128, z = blockIdx.z;
    const unsigned short* A = P   + (size_t)z * 2048 * 4096;   // pitch 4096 ushorts (f32 rows)
    const unsigned short* B = vvT + (size_t)z * 1024 * 2048;   // [d][t]
    float* o = out + (size_t)z * 2048 * 1024;
    f32x4 acc[4][4] = {};
    gemm_core_128(A, B, 4096, 2048, 2048, bm, bn, As, Bs, acc);

    const int tid = threadIdx.x, lane = tid & 63, wave = tid >> 6;
    const int wm = (wave >> 1) * 64, wn = (wave & 1) * 64;
    const int lr = lane & 15, kg = lane >> 4;
    #pragma unroll
    for (int mi = 0; mi < 4; mi++)
        #pragma unroll
        for (int ni = 0; ni < 4; ni++)
            #pragma unroll
            for (int r = 0; r < 4; r++)
                o[(size_t)(bm + wm + mi * 16 + kg * 4 + r) * 1024 + bn + wn + ni * 16 + lr]
                    = acc[mi][ni][r];
}

extern "C" void kernel_launch(void* const* d_in, const int* in_sizes, int n_in,
                              void* d_out, int out_size, void* d_ws, size_t ws_size,
                              hipStream_t stream) {
    const float* x  = (const float*)d_in[0];
    const float* wk = (const float*)d_in[1];
    const float* wq = (const float*)d_in[2];
    const float* wv = (const float*)d_in[3];
    float* out = (float*)d_out;

    char* ws = (char*)d_ws;
    const size_t MB = 1024 * 1024;
    // [0,64MB): xb(16MB) + wT(6MB) during proj; reused as scores(64MB f32) afterwards
    unsigned short* xb  = (unsigned short*)(ws);
    unsigned short* wT  = (unsigned short*)(ws + 16 * MB);
    float*          scores = (float*)(ws);
    unsigned short* vk  = (unsigned short*)(ws + 64 * MB);   // 16MB
    unsigned short* vq  = (unsigned short*)(ws + 80 * MB);   // 16MB
    unsigned short* vvT = (unsigned short*)(ws + 96 * MB);   // 16MB -> 112MB total

    dim3 blk(256);
    convert_x  <<<dim3(4096),      blk, 0, stream>>>(x, xb);
    transpose_w<<<dim3(16, 16, 3), blk, 0, stream>>>(wk, wq, wv, wT);
    proj_gemm  <<<dim3(8, 64, 3),  blk, 0, stream>>>(xb, wT, vk, vq, vvT);
    scores_gemm<<<dim3(16, 16, 4), blk, 0, stream>>>(vk, vq, scores);
    softmax_kernel<<<dim3(8192),   blk, 0, stream>>>(scores);
    pv_gemm    <<<dim3(8, 16, 4),  blk, 0, stream>>>((const unsigned short*)scores, vvT, out);
}

// Round 3
// 190.091 us; speedup vs baseline: 2.5019x; 1.2082x over previous
//
#include <hip/hip_runtime.h>

// B=4, S=2048, D=1024. out = softmax((x@Wk)(x@Wq)^T / 32) @ (x@Wv), fp32 out.
// GEMMs: 8-wave 256-class tiles, BK=64, dbuf LDS, counted vmcnt pipeline,
// XOR-swizzled LDS (inverse-swizzled global src + linear gld_lds dest), XCD swizzle.

typedef __attribute__((ext_vector_type(8))) short bf16x8;
typedef __attribute__((ext_vector_type(4))) float f32x4;

__device__ __forceinline__ unsigned short f2bf(float f) {
    unsigned int u = __float_as_uint(f);
    u += 0x7fff + ((u >> 16) & 1);   // RNE
    return (unsigned short)(u >> 16);
}

__device__ __forceinline__ void gld_lds16(const unsigned short* g, unsigned short* l) {
    // 16B per lane; LDS dest = wave-uniform base + lane*16 (linear)
    __builtin_amdgcn_global_load_lds(
        (const __attribute__((address_space(1))) void*)g,
        (__attribute__((address_space(3))) void*)l, 16, 0, 0);
}

template<int N> __device__ __forceinline__ void vmcnt_wait() {
    if constexpr (N == 0) asm volatile("s_waitcnt vmcnt(0)" ::: "memory");
    else if constexpr (N == 6) asm volatile("s_waitcnt vmcnt(6)" ::: "memory");
    else if constexpr (N == 8) asm volatile("s_waitcnt vmcnt(8)" ::: "memory");
}

// ---------------- pipelined BM x BN x (64*KTILES) bf16 B^T GEMM core ----------------
// C[m,n] = sum_k A[bm+m,k] * B[bn+n,k].  8 waves in 2(m) x 4(n) grid.
// LDS layout: linear [rows][64] bf16 per buffer; 16B unit u of row r holds
// global k-unit (u ^ (r&7))  -> read applies same XOR (T2, rule #21).
template<int BM, int BN, int KTILES>
__device__ __forceinline__ void gemm_pipe(
    const unsigned short* __restrict__ A, const unsigned short* __restrict__ B,
    int lda, int ldb, int bm, int bn,
    unsigned short* As, unsigned short* Bs,
    f32x4 (&acc)[BM/32][BN/64])
{
    constexpr int LA = BM / 64, LB = BN / 64, L = LA + LB;   // gld_lds16 per thread per K-tile
    constexpr int MFR = BM / 32, NFR = BN / 64;              // per-wave 16x16 fragments
    const int tid  = threadIdx.x;
    const int lane = tid & 63;
    const int wave = tid >> 6;
    const int wr = wave >> 2, wc = wave & 3;
    const int lr = lane & 15, kg = lane >> 4;

    // staging: thread t, load i -> LDS row (i*64 + t/8), unit (t&7);
    // inverse-swizzled global source unit = (t&7) ^ ((t/8)&7)
    const int srow = tid >> 3, su = tid & 7;
    const int ssrc = (su ^ (srow & 7)) * 8;
    const unsigned short* pa[LA];
    const unsigned short* pb[LB];
    #pragma unroll
    for (int i = 0; i < LA; i++) pa[i] = A + (size_t)(bm + i * 64 + srow) * lda + ssrc;
    #pragma unroll
    for (int i = 0; i < LB; i++) pb[i] = B + (size_t)(bn + i * 64 + srow) * ldb + ssrc;

    // read-side swizzled unit offsets (row&7 == lr&7 for all frag rows)
    const int pu0 = (kg ^ (lr & 7)) * 8;
    const int pu1 = ((4 + kg) ^ (lr & 7)) * 8;

    auto stage = [&](int cb, int kt) {
        unsigned short* a0 = As + cb * (BM * 64) + wave * 512;   // wave-uniform dests
        unsigned short* b0 = Bs + cb * (BN * 64) + wave * 512;
        #pragma unroll
        for (int i = 0; i < LA; i++) gld_lds16(pa[i] + kt * 64, a0 + i * 4096);
        #pragma unroll
        for (int i = 0; i < LB; i++) gld_lds16(pb[i] + kt * 64, b0 + i * 4096);
    };

    // prologue: 2 tiles in flight, wait tile0 only (counted)
    stage(0, 0);
    stage(1, 1);
    vmcnt_wait<L>();
    __builtin_amdgcn_s_barrier();
    asm volatile("" ::: "memory");

    for (int kt = 0; kt < KTILES; ++kt) {
        const int cb = kt & 1;
        const unsigned short* Ab = As + cb * (BM * 64) + (wr * (BM / 2) + lr) * 64;
        const unsigned short* Bb = Bs + cb * (BN * 64) + (wc * (BN / 4) + lr) * 64;

        bf16x8 bfrag[NFR][2];
        #pragma unroll
        for (int nf = 0; nf < NFR; nf++) {
            bfrag[nf][0] = *reinterpret_cast<const bf16x8*>(Bb + nf * 1024 + pu0);
            bfrag[nf][1] = *reinterpret_cast<const bf16x8*>(Bb + nf * 1024 + pu1);
        }
        __builtin_amdgcn_s_setprio(1);
        #pragma unroll
        for (int mf = 0; mf < MFR; mf++) {
            bf16x8 a0 = *reinterpret_cast<const bf16x8*>(Ab + mf * 1024 + pu0);
            bf16x8 a1 = *reinterpret_cast<const bf16x8*>(Ab + mf * 1024 + pu1);
            #pragma unroll
            for (int nf = 0; nf < NFR; nf++) {
                acc[mf][nf] = __builtin_amdgcn_mfma_f32_16x16x32_bf16(a0, bfrag[nf][0], acc[mf][nf], 0, 0, 0);
                acc[mf][nf] = __builtin_amdgcn_mfma_f32_16x16x32_bf16(a1, bfrag[nf][1], acc[mf][nf], 0, 0, 0);
            }
        }
        __builtin_amdgcn_s_setprio(0);

        asm volatile("" ::: "memory");
        __builtin_amdgcn_s_barrier();        // all waves done reading buf[cb]
        asm volatile("" ::: "memory");
        if (kt + 2 < KTILES) {
            stage(cb, kt + 2);               // overwrite buf[cb] with tile kt+2
            vmcnt_wait<L>();                 // tile kt+1 landed; kt+2 stays in flight
        } else {
            vmcnt_wait<0>();
        }
        __builtin_amdgcn_s_barrier();        // buf[(kt+1)&1] globally ready
        asm volatile("" ::: "memory");
    }
}

// ---------------- x f32 -> bf16 ----------------
__global__ __launch_bounds__(256) void convert_x(
    const float* __restrict__ x, unsigned short* __restrict__ xb)
{
    const size_t idx = (size_t)blockIdx.x * 256 + threadIdx.x;
    const float4* xi = reinterpret_cast<const float4*>(x) + idx * 2;
    float4 v0 = xi[0], v1 = xi[1];
    ushort4 a = { f2bf(v0.x), f2bf(v0.y), f2bf(v0.z), f2bf(v0.w) };
    ushort4 b = { f2bf(v1.x), f2bf(v1.y), f2bf(v1.z), f2bf(v1.w) };
    ushort4* xo = reinterpret_cast<ushort4*>(xb) + idx * 2;
    xo[0] = a; xo[1] = b;
}

// ---------------- W [K][N] f32 -> wT [N][K] bf16 ----------------
__global__ __launch_bounds__(256) void transpose_w(
    const float* __restrict__ w0, const float* __restrict__ w1, const float* __restrict__ w2,
    unsigned short* __restrict__ wT)
{
    __shared__ unsigned short T[64][72];
    const int z = blockIdx.z;
    const float* w = (z == 0) ? w0 : (z == 1 ? w1 : w2);
    unsigned short* o = wT + (size_t)z * 1024 * 1024;
    const int k0 = blockIdx.y * 64, n0 = blockIdx.x * 64;
    const int tid = threadIdx.x;
    const int r = tid >> 4, c4 = (tid & 15) * 4;
    #pragma unroll
    for (int i = 0; i < 4; i++) {
        int kr = r + i * 16;
        float4 v = *reinterpret_cast<const float4*>(&w[(size_t)(k0 + kr) * 1024 + n0 + c4]);
        T[c4 + 0][kr] = f2bf(v.x);
        T[c4 + 1][kr] = f2bf(v.y);
        T[c4 + 2][kr] = f2bf(v.z);
        T[c4 + 3][kr] = f2bf(v.w);
    }
    __syncthreads();
    #pragma unroll
    for (int i = 0; i < 4; i++) {
        int n = r + i * 16;
        ushort4 v = *reinterpret_cast<const ushort4*>(&T[n][c4]);
        *reinterpret_cast<ushort4*>(&o[(size_t)(n0 + n) * 1024 + k0 + c4]) = v;
    }
}

// ---------------- projections: 128x256 tiles, grid 768 = 3/CU ----------------
__global__ __launch_bounds__(512, 2) void proj_gemm(
    const unsigned short* __restrict__ xb, const unsigned short* __restrict__ wT,
    unsigned short* __restrict__ vk, unsigned short* __restrict__ vq,
    unsigned short* __restrict__ vvT)
{
    __shared__ unsigned short As[2 * 128 * 64], Bs[2 * 256 * 64];   // 96 KB
    const int bid = blockIdx.x;
    const int wg  = (bid & 7) * 96 + (bid >> 3);   // XCD swizzle, 768 % 8 == 0
    const int z   = wg >> 8;
    const int rem = wg & 255;
    const int bm  = (rem >> 2) * 128;
    const int bn  = (rem & 3) * 256;
    const unsigned short* Bw = wT + (size_t)z * 1024 * 1024;

    f32x4 acc[4][4] = {};
    gemm_pipe<128, 256, 16>(xb, Bw, 1024, 1024, bm, bn, As, Bs, acc);

    const int tid = threadIdx.x, lane = tid & 63, wave = tid >> 6;
    const int wr = wave >> 2, wc = wave & 3, lr = lane & 15, kg = lane >> 4;
    if (z < 2) {
        unsigned short* out = z ? vq : vk;
        #pragma unroll
        for (int mf = 0; mf < 4; mf++)
            #pragma unroll
            for (int nf = 0; nf < 4; nf++)
                #pragma unroll
                for (int r = 0; r < 4; r++)
                    out[(size_t)(bm + wr * 64 + mf * 16 + kg * 4 + r) * 1024
                        + bn + wc * 64 + nf * 16 + lr] = f2bf(acc[mf][nf][r]);
    } else {
        const int batch = bm >> 11;                 // 128-tiles never span batches
        const int rb0 = (bm & 2047) + wr * 64;
        unsigned short* o = vvT + (size_t)batch * 1024 * 2048;
        #pragma unroll
        for (int mf = 0; mf < 4; mf++)
            #pragma unroll
            for (int nf = 0; nf < 4; nf++) {
                ushort4 v = { f2bf(acc[mf][nf][0]), f2bf(acc[mf][nf][1]),
                              f2bf(acc[mf][nf][2]), f2bf(acc[mf][nf][3]) };
                *reinterpret_cast<ushort4*>(
                    &o[(size_t)(bn + wc * 64 + nf * 16 + lr) * 2048 + rb0 + mf * 16 + kg * 4]) = v;
            }
    }
}

// ---------------- scores: 256x256 tiles, grid 256 = 1/CU ----------------
__global__ __launch_bounds__(512, 2) void scores_gemm(
    const unsigned short* __restrict__ vk, const unsigned short* __restrict__ vq,
    float* __restrict__ scores)
{
    __shared__ unsigned short As[2 * 256 * 64], Bs[2 * 256 * 64];   // 128 KB
    const int bid = blockIdx.x;
    const int wg  = (bid & 7) * 32 + (bid >> 3);
    const int z   = wg >> 6;
    const int rem = wg & 63;
    const int bm  = (rem >> 3) * 256;
    const int bn  = (rem & 7) * 256;
    const unsigned short* A = vk + (size_t)z * 2048 * 1024;
    const unsigned short* B = vq + (size_t)z * 2048 * 1024;
    float* out = scores + (size_t)z * 2048 * 2048;

    f32x4 acc[8][4] = {};
    gemm_pipe<256, 256, 16>(A, B, 1024, 1024, bm, bn, As, Bs, acc);

    const int tid = threadIdx.x, lane = tid & 63, wave = tid >> 6;
    const int wr = wave >> 2, wc = wave & 3, lr = lane & 15, kg = lane >> 4;
    #pragma unroll
    for (int mf = 0; mf < 8; mf++)
        #pragma unroll
        for (int nf = 0; nf < 4; nf++)
            #pragma unroll
            for (int r = 0; r < 4; r++)
                out[(size_t)(bm + wr * 128 + mf * 16 + kg * 4 + r) * 2048
                    + bn + wc * 64 + nf * 16 + lr] = acc[mf][nf][r] * 0.03125f;
}

// ---------------- softmax; bf16 P in-place over first half of each f32 row ----------------
__global__ __launch_bounds__(256) void softmax_kernel(float* __restrict__ scores)
{
    const size_t row = blockIdx.x;
    float* p = scores + row * 2048;
    const int tid  = threadIdx.x;
    const int lane = tid & 63;
    const int wave = tid >> 6;

    float4 v0 = *reinterpret_cast<const float4*>(&p[tid * 8]);
    float4 v1 = *reinterpret_cast<const float4*>(&p[tid * 8 + 4]);
    float v[8] = { v0.x, v0.y, v0.z, v0.w, v1.x, v1.y, v1.z, v1.w };

    float mx = v[0];
    #pragma unroll
    for (int i = 1; i < 8; i++) mx = fmaxf(mx, v[i]);
    #pragma unroll
    for (int off = 32; off >= 1; off >>= 1) mx = fmaxf(mx, __shfl_xor(mx, off));

    __shared__ float redm[4], reds[4];
    if (lane == 0) redm[wave] = mx;
    __syncthreads();
    mx = fmaxf(fmaxf(redm[0], redm[1]), fmaxf(redm[2], redm[3]));

    float e[8], sum = 0.f;
    #pragma unroll
    for (int i = 0; i < 8; i++) { e[i] = __expf(v[i] - mx); sum += e[i]; }
    #pragma unroll
    for (int off = 32; off >= 1; off >>= 1) sum += __shfl_xor(sum, off);
    if (lane == 0) reds[wave] = sum;
    __syncthreads();
    const float inv = 1.0f / (reds[0] + reds[1] + reds[2] + reds[3]);

    unsigned short o[8];
    #pragma unroll
    for (int i = 0; i < 8; i++) o[i] = f2bf(e[i] * inv);
    uint4 packed;
    packed.x = (unsigned)o[0] | ((unsigned)o[1] << 16);
    packed.y = (unsigned)o[2] | ((unsigned)o[3] << 16);
    packed.z = (unsigned)o[4] | ((unsigned)o[5] << 16);
    packed.w = (unsigned)o[6] | ((unsigned)o[7] << 16);
    reinterpret_cast<uint4*>(p)[tid] = packed;
}

// ---------------- PV: 256x128 tiles, K=2048, grid 256 = 1/CU ----------------
__global__ __launch_bounds__(512, 2) void pv_gemm(
    const unsigned short* __restrict__ P, const unsigned short* __restrict__ vvT,
    float* __restrict__ out)
{
    __shared__ unsigned short As[2 * 256 * 64], Bs[2 * 128 * 64];   // 96 KB
    const int bid = blockIdx.x;
    const int wg  = (bid & 7) * 32 + (bid >> 3);
    const int z   = wg >> 6;
    const int rem = wg & 63;
    const int bm  = (rem >> 3) * 256;
    const int bn  = (rem & 7) * 128;
    const unsigned short* A = P   + (size_t)z * 2048 * 4096;   // bf16 in f32-pitch rows
    const unsigned short* B = vvT + (size_t)z * 1024 * 2048;
    float* o = out + (size_t)z * 2048 * 1024;

    f32x4 acc[8][2] = {};
    gemm_pipe<256, 128, 32>(A, B, 4096, 2048, bm, bn, As, Bs, acc);

    const int tid = threadIdx.x, lane = tid & 63, wave = tid >> 6;
    const int wr = wave >> 2, wc = wave & 3, lr = lane & 15, kg = lane >> 4;
    #pragma unroll
    for (int mf = 0; mf < 8; mf++)
        #pragma unroll
        for (int nf = 0; nf < 2; nf++)
            #pragma unroll
            for (int r = 0; r < 4; r++)
                o[(size_t)(bm + wr * 128 + mf * 16 + kg * 4 + r) * 1024
                  + bn + wc * 32 + nf * 16 + lr] = acc[mf][nf][r];
}

extern "C" void kernel_launch(void* const* d_in, const int* in_sizes, int n_in,
                              void* d_out, int out_size, void* d_ws, size_t ws_size,
                              hipStream_t stream) {
    const float* x  = (const float*)d_in[0];
    const float* wk = (const float*)d_in[1];
    const float* wq = (const float*)d_in[2];
    const float* wv = (const float*)d_in[3];
    float* out = (float*)d_out;

    char* ws = (char*)d_ws;
    const size_t MB = 1024 * 1024;
    unsigned short* xb  = (unsigned short*)(ws);
    unsigned short* wT  = (unsigned short*)(ws + 16 * MB);
    float*          scores = (float*)(ws);                    // aliases xb+wT (dead after proj)
    unsigned short* vk  = (unsigned short*)(ws + 64 * MB);
    unsigned short* vq  = (unsigned short*)(ws + 80 * MB);
    unsigned short* vvT = (unsigned short*)(ws + 96 * MB);

    convert_x     <<<dim3(4096),      256, 0, stream>>>(x, xb);
    transpose_w   <<<dim3(16, 16, 3), 256, 0, stream>>>(wk, wq, wv, wT);
    proj_gemm     <<<dim3(768),       512, 0, stream>>>(xb, wT, vk, vq, vvT);
    scores_gemm   <<<dim3(256),       512, 0, stream>>>(vk, vq, scores);
    softmax_kernel<<<dim3(8192),      256, 0, stream>>>(scores);
    pv_gemm       <<<dim3(256),       512, 0, stream>>>((const unsigned short*)scores, vvT, out);
}